// Round 10
// baseline (2866.859 us; speedup 1.0000x reference)
//
#include <hip/hip_runtime.h>
#include <stdint.h>

typedef short s16x8 __attribute__((ext_vector_type(8)));
typedef float f32x4 __attribute__((ext_vector_type(4)));
typedef uint32_t u32x2 __attribute__((ext_vector_type(2)));

#define LSEG 511

static __device__ __forceinline__ uint32_t cvt_pk_bf16(float lo, float hi) {
  uint32_t r;
  asm("v_cvt_pk_bf16_f32 %0, %1, %2" : "=v"(r) : "v"(lo), "v"(hi));
  return r;
}
static __device__ __forceinline__ unsigned short f2bf(float f) {
  union { float f; uint32_t u; } v; v.f = f;
  uint32_t r = (v.u + 0x7FFFu + ((v.u >> 16) & 1u)) >> 16;
  return (unsigned short)r;
}

// Swapped-operand design: every layer computed as OUT^T = W^T (A) · IN^T (B).
//  - B-frags (activations, col=batch=lr, k=channel) read from LDS with the
//    SAME swizzled b128 pattern as before.
//  - D-frags: col=batch (lr), rows = 4 consecutive output channels per lane
//    -> epilogue = 2 cvt_pk + ONE ds_write_b64, conflict-free, no dpp.
//  - W_out A-rows permuted so lane's 4 acc = 4 c's of one h for its OWN
//    batch row: einsum = 4 fma + one shfl_xor(32); dx read = 1 b128.
// 16 batch rows/block, 8 all-active waves, 1 block/CU, 4 barriers/RK-stage.
// tanh prescale (W_out,b_out x 2log2e): tanh = 1 - 2*rcp(exp2(acc)+1).
__global__ __attribute__((amdgpu_flat_work_group_size(512, 512),
                          amdgpu_waves_per_eu(2, 2)))
void cde_kernel(
    const float* __restrict__ coeffs,
    const float* __restrict__ W_init, const float* __restrict__ b_init,
    const float* __restrict__ W_in,  const float* __restrict__ b_in,
    const float* __restrict__ W_h,   const float* __restrict__ b_h,
    const float* __restrict__ W_out, const float* __restrict__ b_out,
    const float* __restrict__ W_read,const float* __restrict__ b_read,
    float* __restrict__ out)
{
  __shared__ __align__(16) char H1mem[16 * 256];
  __shared__ __align__(16) char H2mem[16 * 256];
  __shared__ __align__(16) char Xmem[16 * 128];
  __shared__ float dx2[4][16][8];        // [s][batch][c]

  const int tid  = threadIdx.x;
  const int w    = tid >> 6;     // wave 0..7
  const int lane = tid & 63;
  const int lr   = lane & 15;    // batch row (B-frag col / A-frag row)
  const int lk   = lane >> 4;    // k-subgroup / D-row-group
  const int b0   = blockIdx.x * 16;

  const float TS = 2.8853900817779268f;   // 2*log2(e)

  // ---- weight A-frags (A layout: row=lr, k=32*kq+8*lk+e) ----
  // L1-3: A row lr <-> out-ch 16w+lr  (same values as the old B-frags)
  s16x8 Win_f[2], Wh0_f[4], Wh1_f[4], Wout_f[4][4];
  const int wc = 16*w + lr;
  #pragma unroll
  for (int kq = 0; kq < 2; ++kq)
    #pragma unroll
    for (int e = 0; e < 8; ++e)
      Win_f[kq][e] = (short)f2bf(W_in[(32*kq + 8*lk + e)*128 + wc]);
  #pragma unroll
  for (int kq = 0; kq < 4; ++kq)
    #pragma unroll
    for (int e = 0; e < 8; ++e) {
      Wh0_f[kq][e] = (short)f2bf(W_h[(32*kq + 8*lk + e)*128 + wc]);
      Wh1_f[kq][e] = (short)f2bf(W_h[16384 + (32*kq + 8*lk + e)*128 + wc]);
    }
  // L4: A row lr <-> ch = (8w + 2nt + ((lr>>2)&1))*8 + (lr&3) + 4*((lr>>3)&1)
  #pragma unroll
  for (int kq = 0; kq < 4; ++kq)
    #pragma unroll
    for (int nt = 0; nt < 4; ++nt) {
      const int ch = (8*w + 2*nt + ((lr >> 2) & 1))*8 + (lr & 3) + 4*((lr >> 3) & 1);
      #pragma unroll
      for (int e = 0; e < 8; ++e)
        Wout_f[kq][nt][e] = (short)f2bf(W_out[(32*kq + 8*lk + e)*512 + ch] * TS);
    }
  // per-row bias C-in vectors: element r = bias[out-ch(row 4lk+r)]
  f32x4 bin4, bh04, bh14, bout4[4];
  #pragma unroll
  for (int r = 0; r < 4; ++r) {
    bin4[r] = b_in[16*w + 4*lk + r];
    bh04[r] = b_h[16*w + 4*lk + r];
    bh14[r] = b_h[128 + 16*w + 4*lk + r];
  }
  #pragma unroll
  for (int nt = 0; nt < 4; ++nt)
    #pragma unroll
    for (int r = 0; r < 4; ++r)
      bout4[nt][r] = b_out[(8*w + 2*nt + (lk & 1))*8 + 4*(lk >> 1) + r] * TS;

  // ---- precomputed LDS byte offsets ----
  int vb[4];                        // H B-frag reads: row=lr, blk=(4kq+lk)^swz
  #pragma unroll
  for (int kq = 0; kq < 4; ++kq)
    vb[kq] = lr*256 + (((4*kq + lk) ^ (lr & 7)) << 4);
  const int vbX0 = lr*128 + ((lk ^ (lr & 7)) << 4);
  const int vbX1 = vbX0 ^ 64;
  // H write (one b64): batch=lr, chs 16w+4lk..+3 -> blk 2w+(lk>>1), half lk&1
  const int wbH = lr*256 + (((2*w + (lk >> 1)) ^ (lr & 7)) << 4) + (lk & 1)*8;
  // X writes (4 b16, lanes lk<2): h' = 2nt+(lk&1), blk=w
  int wbXh[4];
  #pragma unroll
  for (int nt = 0; nt < 4; ++nt)
    wbXh[nt] = lr*128 + ((w ^ (lr & 7)) << 4) + 2*(2*nt + (lk & 1));
  const int dbx = lr*32 + (lk >> 1)*16;   // dx2 read base: + s*512

  // ---- z0 init: lane owns batch lr, h's {8w + 2nt + (lk&1)} ----
  float z0[4], zfin[4], k1r[4], k2r[4];
  {
    const float* a0r = &coeffs[(size_t)(b0 + lr) * (LSEG*32)];
    #pragma unroll
    for (int nt = 0; nt < 4; ++nt) {
      const int h = 8*w + 2*nt + (lk & 1);
      float s = b_init[h];
      #pragma unroll
      for (int c = 0; c < 8; ++c) s = fmaf(a0r[c], W_init[c*64 + h], s);
      z0[nt] = s; zfin[nt] = 0.f; k1r[nt] = 0.f; k2r[nt] = 0.f;
    }
    if (lk < 2) {
      #pragma unroll
      for (int nt = 0; nt < 4; ++nt)
        *(unsigned short*)(Xmem + wbXh[nt]) = (unsigned short)cvt_pk_bf16(z0[nt], z0[nt]);
    }
  }

  // ---- coeff prefetch regs: 16 lanes/wave, 2 rows/wave ----
  float cf_b = 0.f, cf_c = 0.f, cf_d = 0.f;
  const int crow = 2*w + (lane >> 5);
  const int ccc  = (lane >> 2) & 7;
  const bool cact = (lane & 3) == 0;
  if (cact) {
    const float* cp = &coeffs[(size_t)(b0 + crow)*(LSEG*32)];
    cf_b = cp[8+ccc]; cf_c = cp[16+ccc]; cf_d = cp[24+ccc];
  }
  __syncthreads();

  #pragma unroll 1
  for (int t = 0; t < LSEG; ++t) {
    #pragma unroll
    for (int s = 0; s < 4; ++s) {
      // =============== P1: (dx2 @ s==0) + L1: X -> H1 ===============
      if (s == 0 && cact) {
        const float third = 1.f/3.f, two3 = 2.f/3.f;
        float* dp = &dx2[0][crow][ccc];
        dp[0]   = cf_b;
        dp[128] = fmaf(fmaf(cf_d, third, cf_c), third, cf_b);
        dp[256] = fmaf(fmaf(cf_d, two3, cf_c), two3, cf_b);
        dp[384] = cf_b + cf_c + cf_d;
        if (t + 1 < LSEG) {
          const float* cp = &coeffs[((size_t)(b0 + crow)*LSEG + (t+1))*32];
          cf_b = cp[8+ccc]; cf_c = cp[16+ccc]; cf_d = cp[24+ccc];
        }
      }
      {
        s16x8 a0 = *(const s16x8*)(Xmem + vbX0);
        s16x8 a1 = *(const s16x8*)(Xmem + vbX1);
        __builtin_amdgcn_s_setprio(1);
        f32x4 acc;
        acc = __builtin_amdgcn_mfma_f32_16x16x32_bf16(Win_f[0], a0, bin4, 0, 0, 0);
        acc = __builtin_amdgcn_mfma_f32_16x16x32_bf16(Win_f[1], a1, acc, 0, 0, 0);
        __builtin_amdgcn_s_setprio(0);
        u32x2 pk;
        pk[0] = cvt_pk_bf16(fmaxf(acc[0], 0.f), fmaxf(acc[1], 0.f));
        pk[1] = cvt_pk_bf16(fmaxf(acc[2], 0.f), fmaxf(acc[3], 0.f));
        *(u32x2*)(H1mem + wbH) = pk;
      }
      __syncthreads();

      // =============== P2: L2: H1 -> H2 ===============
      {
        s16x8 a0 = *(const s16x8*)(H1mem + vb[0]);
        s16x8 a1 = *(const s16x8*)(H1mem + vb[1]);
        s16x8 a2 = *(const s16x8*)(H1mem + vb[2]);
        s16x8 a3 = *(const s16x8*)(H1mem + vb[3]);
        __builtin_amdgcn_s_setprio(1);
        f32x4 acc0, acc1 = {};
        acc0 = __builtin_amdgcn_mfma_f32_16x16x32_bf16(Wh0_f[0], a0, bh04, 0, 0, 0);
        acc1 = __builtin_amdgcn_mfma_f32_16x16x32_bf16(Wh0_f[1], a1, acc1, 0, 0, 0);
        acc0 = __builtin_amdgcn_mfma_f32_16x16x32_bf16(Wh0_f[2], a2, acc0, 0, 0, 0);
        acc1 = __builtin_amdgcn_mfma_f32_16x16x32_bf16(Wh0_f[3], a3, acc1, 0, 0, 0);
        __builtin_amdgcn_s_setprio(0);
        f32x4 acc = acc0 + acc1;
        u32x2 pk;
        pk[0] = cvt_pk_bf16(fmaxf(acc[0], 0.f), fmaxf(acc[1], 0.f));
        pk[1] = cvt_pk_bf16(fmaxf(acc[2], 0.f), fmaxf(acc[3], 0.f));
        *(u32x2*)(H2mem + wbH) = pk;
      }
      __syncthreads();

      // =============== P3: L3: H2 -> H1 ===============
      {
        s16x8 a0 = *(const s16x8*)(H2mem + vb[0]);
        s16x8 a1 = *(const s16x8*)(H2mem + vb[1]);
        s16x8 a2 = *(const s16x8*)(H2mem + vb[2]);
        s16x8 a3 = *(const s16x8*)(H2mem + vb[3]);
        __builtin_amdgcn_s_setprio(1);
        f32x4 acc0, acc1 = {};
        acc0 = __builtin_amdgcn_mfma_f32_16x16x32_bf16(Wh1_f[0], a0, bh14, 0, 0, 0);
        acc1 = __builtin_amdgcn_mfma_f32_16x16x32_bf16(Wh1_f[1], a1, acc1, 0, 0, 0);
        acc0 = __builtin_amdgcn_mfma_f32_16x16x32_bf16(Wh1_f[2], a2, acc0, 0, 0, 0);
        acc1 = __builtin_amdgcn_mfma_f32_16x16x32_bf16(Wh1_f[3], a3, acc1, 0, 0, 0);
        __builtin_amdgcn_s_setprio(0);
        f32x4 acc = acc0 + acc1;
        u32x2 pk;
        pk[0] = cvt_pk_bf16(fmaxf(acc[0], 0.f), fmaxf(acc[1], 0.f));
        pk[1] = cvt_pk_bf16(fmaxf(acc[2], 0.f), fmaxf(acc[3], 0.f));
        *(u32x2*)(H1mem + wbH) = pk;
      }
      __syncthreads();

      // ========= P4: L4 + tanh + einsum + RK state + X write =========
      {
        f32x4 dxv = *(const f32x4*)((const char*)dx2 + s*512 + dbx);
        s16x8 a0 = *(const s16x8*)(H1mem + vb[0]);
        s16x8 a1 = *(const s16x8*)(H1mem + vb[1]);
        s16x8 a2 = *(const s16x8*)(H1mem + vb[2]);
        s16x8 a3 = *(const s16x8*)(H1mem + vb[3]);
        __builtin_amdgcn_s_setprio(1);
        f32x4 acc[4];
        #pragma unroll
        for (int nt = 0; nt < 4; ++nt)
          acc[nt] = __builtin_amdgcn_mfma_f32_16x16x32_bf16(Wout_f[0][nt], a0, bout4[nt], 0, 0, 0);
        #pragma unroll
        for (int nt = 0; nt < 4; ++nt)
          acc[nt] = __builtin_amdgcn_mfma_f32_16x16x32_bf16(Wout_f[1][nt], a1, acc[nt], 0, 0, 0);
        #pragma unroll
        for (int nt = 0; nt < 4; ++nt)
          acc[nt] = __builtin_amdgcn_mfma_f32_16x16x32_bf16(Wout_f[2][nt], a2, acc[nt], 0, 0, 0);
        #pragma unroll
        for (int nt = 0; nt < 4; ++nt)
          acc[nt] = __builtin_amdgcn_mfma_f32_16x16x32_bf16(Wout_f[3][nt], a3, acc[nt], 0, 0, 0);
        __builtin_amdgcn_s_setprio(0);
        #pragma unroll
        for (int nt = 0; nt < 4; ++nt) {
          float sum = 0.f;
          #pragma unroll
          for (int r = 0; r < 4; ++r) {
            // acc pre-scaled by 2*log2(e): tanh = 1 - 2*rcp(exp2(acc)+1)
            float e2 = __builtin_amdgcn_exp2f(acc[nt][r]);
            float rr = __builtin_amdgcn_rcpf(e2 + 1.f);
            float tv = fmaf(-2.f, rr, 1.f);
            sum = fmaf(tv, dxv[r], sum);
          }
          sum += __shfl_xor(sum, 32);   // add c-half from lane lk^2 (same batch, same h)
          float znext;
          if (s == 0) {
            k1r[nt] = sum;
            zfin[nt] = fmaf(0.125f, sum, z0[nt]);
            znext    = fmaf(1.f/3.f, sum, z0[nt]);
          } else if (s == 1) {
            k2r[nt] = sum;
            zfin[nt] = fmaf(0.375f, sum, zfin[nt]);
            znext    = z0[nt] + sum - (1.f/3.f)*k1r[nt];
          } else if (s == 2) {
            zfin[nt] = fmaf(0.375f, sum, zfin[nt]);
            znext    = z0[nt] + k1r[nt] - k2r[nt] + sum;
          } else {
            zfin[nt] = fmaf(0.125f, sum, zfin[nt]);
            znext    = zfin[nt];
            z0[nt]   = zfin[nt];
          }
          if (lk < 2)
            *(unsigned short*)(Xmem + wbXh[nt]) = (unsigned short)cvt_pk_bf16(znext, znext);
        }
      }
      __syncthreads();
    }
  }

  // ---- readout: stage z0 (fp32) into H1 bytes, then dot W_read ----
  float* ZF = (float*)H1mem;   // plain [16][64] floats
  if (lk < 2) {
    #pragma unroll
    for (int nt = 0; nt < 4; ++nt)
      ZF[lr*64 + 8*w + 2*nt + (lk & 1)] = z0[nt];
  }
  __syncthreads();
  if (tid < 16) {
    float acc = b_read[0];
    for (int h = 0; h < 64; ++h) acc = fmaf(ZF[tid*64 + h], W_read[h], acc);
    out[b0 + tid] = acc;
  }
}

extern "C" void kernel_launch(void* const* d_in, const int* in_sizes, int n_in,
                              void* d_out, int out_size, void* d_ws, size_t ws_size,
                              hipStream_t stream) {
  const float* coeffs = (const float*)d_in[0];
  const float* W_init = (const float*)d_in[1];
  const float* b_init = (const float*)d_in[2];
  const float* W_in   = (const float*)d_in[3];
  const float* b_in   = (const float*)d_in[4];
  const float* W_h    = (const float*)d_in[5];
  const float* b_h    = (const float*)d_in[6];
  const float* W_out  = (const float*)d_in[7];
  const float* b_out  = (const float*)d_in[8];
  const float* W_read = (const float*)d_in[9];
  const float* b_read = (const float*)d_in[10];
  float* out = (float*)d_out;

  cde_kernel<<<dim3(256), dim3(512), 0, stream>>>(
      coeffs, W_init, b_init, W_in, b_in, W_h, b_h, W_out, b_out,
      W_read, b_read, out);
}